// Round 5
// baseline (271.882 us; speedup 1.0000x reference)
//
#include <hip/hip_runtime.h>
#include <math.h>

#define HW_     (1024 * 1024)
#define NPIX    (4 * HW_)               // 4,194,304 pixels
#define NG      (NPIX / 4)              // 1,048,576 float4 groups
#define NSETS   64
#define ACC_STRIDE 32                   // doubles/set: 0..7 sx, 8..15 sy, 16..23 cnt, 24 spw, 25 sxx
#define BLOCK_  256
#define GRID1   (NG / BLOCK_)           // 4096 blocks, one float4-group per thread

// fast pow for x>0: v_log_f32 (log2) + v_mul + v_exp_f32 (exp2)
__device__ __forceinline__ float fast_pow_pos(float x, float p) {
    return __builtin_amdgcn_exp2f(p * __builtin_amdgcn_logf(x));
}

// One float4 group (4 consecutive pixels) per thread.
//
// MLP-forcing mechanism (round 5): plain float4 loads + SEMANTIC keep-alive
// fences. Each fence is an empty asm volatile with a "memory" clobber that
// names load results as input-only SCALAR "v" operands (round 4's "+v" on a
// float4 is a tied indirect operand -> backend error; input-only scalars are
// single-register, always legal). Because of the "memory" clobber, loads
// cannot sink past a fence and values cannot be rematerialized after it:
// all 14 loads must issue before fence 1 and all 56 result VGPRs are live
// there. This is a semantic constraint, not a scheduler hint (rounds 1-2
// showed hints are ignored: VGPR stayed 32).
__global__ __launch_bounds__(BLOCK_, 4) void pass1_kernel(
    const float* __restrict__ x, const float* __restrict__ y,
    const float* __restrict__ mk, double* __restrict__ acc)
{
    const int g  = blockIdx.x * BLOCK_ + threadIdx.x;
    const int p0 = g << 2;
    const int b  = p0 >> 20;            // HW_ = 2^20
    const int hw = p0 & (HW_ - 1);

    const size_t xb = (size_t)(b * 3) * HW_ + hw;
    const size_t mb = (size_t)(b * 8) * HW_ + hw;

    // ---- 14 independent vector loads, issued as one batch ----
    float4 x0 = *(const float4*)(x + xb);
    float4 x1 = *(const float4*)(x + xb + HW_);
    float4 x2 = *(const float4*)(x + xb + 2 * (size_t)HW_);
    float4 y0 = *(const float4*)(y + xb);
    float4 y1 = *(const float4*)(y + xb + HW_);
    float4 y2 = *(const float4*)(y + xb + 2 * (size_t)HW_);
    float4 m0 = *(const float4*)(mk + mb);
    float4 m1 = *(const float4*)(mk + mb + 1 * (size_t)HW_);
    float4 m2 = *(const float4*)(mk + mb + 2 * (size_t)HW_);
    float4 m3 = *(const float4*)(mk + mb + 3 * (size_t)HW_);
    float4 m4 = *(const float4*)(mk + mb + 4 * (size_t)HW_);
    float4 m5 = *(const float4*)(mk + mb + 5 * (size_t)HW_);
    float4 m6 = *(const float4*)(mk + mb + 6 * (size_t)HW_);
    float4 m7 = *(const float4*)(mk + mb + 7 * (size_t)HW_);

    // Fence 1: x,y results live (waits vmcnt(8): masks still in flight).
    asm volatile("" :
        : "v"(x0.x), "v"(x0.y), "v"(x0.z), "v"(x0.w),
          "v"(x1.x), "v"(x1.y), "v"(x1.z), "v"(x1.w),
          "v"(x2.x), "v"(x2.y), "v"(x2.z), "v"(x2.w),
          "v"(y0.x), "v"(y0.y), "v"(y0.z), "v"(y0.w),
          "v"(y1.x), "v"(y1.y), "v"(y1.z), "v"(y1.w),
          "v"(y2.x), "v"(y2.y), "v"(y2.z), "v"(y2.w)
        : "memory");
    // Fence 2: first half of masks live.
    asm volatile("" :
        : "v"(m0.x), "v"(m0.y), "v"(m0.z), "v"(m0.w),
          "v"(m1.x), "v"(m1.y), "v"(m1.z), "v"(m1.w),
          "v"(m2.x), "v"(m2.y), "v"(m2.z), "v"(m2.w),
          "v"(m3.x), "v"(m3.y), "v"(m3.z), "v"(m3.w)
        : "memory");
    // Fence 3: second half of masks live.
    asm volatile("" :
        : "v"(m4.x), "v"(m4.y), "v"(m4.z), "v"(m4.w),
          "v"(m5.x), "v"(m5.y), "v"(m5.z), "v"(m5.w),
          "v"(m6.x), "v"(m6.y), "v"(m6.z), "v"(m6.w),
          "v"(m7.x), "v"(m7.y), "v"(m7.z), "v"(m7.w)
        : "memory");

    float sx[8], sy[8], sc[8];
#pragma unroll
    for (int l = 0; l < 8; ++l) { sx[l] = 0.f; sy[l] = 0.f; sc[l] = 0.f; }
    float spw = 0.f, sxx = 0.f;

    const float inv3 = 1.0f / 3.0f;     // mul, not the v_div_* sequence

    // strict >: first occurrence wins (jnp.argmax tie-break)
#define PIX(F)                                                              \
    {                                                                       \
        const float xav = (x0.F + x1.F + x2.F) * inv3;                      \
        const float yav = (y0.F + y1.F + y2.F) * inv3;                      \
        float best = m0.F; int bi = 0;                                      \
        if (m1.F > best) { best = m1.F; bi = 1; }                           \
        if (m2.F > best) { best = m2.F; bi = 2; }                           \
        if (m3.F > best) { best = m3.F; bi = 3; }                           \
        if (m4.F > best) { best = m4.F; bi = 4; }                           \
        if (m5.F > best) { best = m5.F; bi = 5; }                           \
        if (m6.F > best) { best = m6.F; bi = 6; }                           \
        if (m7.F > best) { best = m7.F; bi = 7; }                           \
        _Pragma("unroll")                                                   \
        for (int l = 0; l < 8; ++l) {                                       \
            const bool p = (bi == l);                                       \
            sx[l] += p ? xav : 0.0f;                                        \
            sy[l] += p ? yav : 0.0f;                                        \
            sc[l] += p ? 1.0f : 0.0f;                                       \
        }                                                                   \
        spw += fast_pow_pos(xav, yav);  /* xav>0: mean of uniforms */       \
        sxx += xav * xav;                                                   \
    }

    PIX(x) PIX(y) PIX(z) PIX(w)
#undef PIX

    // ---- wave64 shuffle reduction of the 26 accumulators ----
#pragma unroll
    for (int off = 32; off > 0; off >>= 1) {
#pragma unroll
        for (int l = 0; l < 8; ++l) {
            sx[l] += __shfl_down(sx[l], off);
            sy[l] += __shfl_down(sy[l], off);
            sc[l] += __shfl_down(sc[l], off);
        }
        spw += __shfl_down(spw, off);
        sxx += __shfl_down(sxx, off);
    }
    __shared__ float red[4][26];
    const int wave = threadIdx.x >> 6, lane = threadIdx.x & 63;
    if (lane == 0) {
#pragma unroll
        for (int l = 0; l < 8; ++l) {
            red[wave][l]      = sx[l];
            red[wave][8 + l]  = sy[l];
            red[wave][16 + l] = sc[l];
        }
        red[wave][24] = spw;
        red[wave][25] = sxx;
    }
    __syncthreads();
    if (threadIdx.x < 26) {
        float t = red[0][threadIdx.x] + red[1][threadIdx.x] +
                  red[2][threadIdx.x] + red[3][threadIdx.x];
        atomicAdd(&acc[(blockIdx.x & (NSETS - 1)) * ACC_STRIDE + threadIdx.x],
                  (double)t);
    }
}

// ---- finalize: all three losses in f64, write 3 floats ----
__global__ void finalize_kernel(const double* __restrict__ acc,
                                float* __restrict__ out)
{
    __shared__ double sh[26];
    int t = threadIdx.x;
    if (t < 26) {
        double s = 0.0;
        for (int k = 0; k < NSETS; ++k) s += acc[k * ACC_STRIDE + t];
        sh[t] = s;
    }
    __syncthreads();
    if (t == 0) {
        const double invN = 1.0 / (double)NPIX;
        double l1 = sh[24];       // sum of pow over on-mask pixels
        double l3 = sh[25];       // sum of xa^2
        double l2 = 0.0;
        for (int l = 0; l < 8; ++l) {
            double SX  = sh[l];
            double XA  = SX * invN;
            double YA  = sh[8 + l] * invN;
            double cnt = sh[16 + l];
            double pw  = pow(XA, YA);
            l2 += pw;
            l1 += ((double)NPIX - cnt) * pw;          // off-mask pow terms
            l3 += cnt * XA * XA - 2.0 * XA * SX;      // per-label variance cross terms
        }
        out[0] = (float)(l1 * invN);
        out[1] = (float)l2;
        out[2] = (float)(l3 * invN);
    }
}

extern "C" void kernel_launch(void* const* d_in, const int* in_sizes, int n_in,
                              void* d_out, int out_size, void* d_ws, size_t ws_size,
                              hipStream_t stream)
{
    const float* x  = (const float*)d_in[0];
    const float* y  = (const float*)d_in[1];
    const float* mk = (const float*)d_in[2];
    float* out = (float*)d_out;

    double* acc = (double*)d_ws;                    // 64*32*8 = 16 KB
    (void)hipMemsetAsync(acc, 0, NSETS * ACC_STRIDE * 8, stream);

    pass1_kernel<<<GRID1, BLOCK_, 0, stream>>>(x, y, mk, acc);
    finalize_kernel<<<1, 64, 0, stream>>>(acc, out);
}

// Round 6
// 269.500 us; speedup vs baseline: 1.0088x; 1.0088x over previous
//
#include <hip/hip_runtime.h>
#include <math.h>

#define HW_     (1024 * 1024)
#define NPIX    (4 * HW_)               // 4,194,304 pixels
#define NG      (NPIX / 4)              // 1,048,576 float4 groups
#define NSETS   64
#define ACC_STRIDE 32                   // doubles/set: 0..7 sx, 8..15 sy, 16..23 cnt, 24 spw, 25 sxx
#define BLOCK_  256
#define GRID1   (NG / BLOCK_)           // 4096 blocks, one float4-group per thread

// fast pow for x>0: v_log_f32 (log2) + v_mul + v_exp_f32 (exp2)
__device__ __forceinline__ float fast_pow_pos(float x, float p) {
    return __builtin_amdgcn_exp2f(p * __builtin_amdgcn_logf(x));
}

// Async global->LDS 16B/lane copy. Side-effecting intrinsic: the compiler
// MUST issue it at its program point, in order, and the data never touches
// VGPRs -- this is the only load form the scheduler cannot serialize for
// register-pressure reasons (rounds 1-5: every VGPR-path forcing attempt was
// defeated, VGPR pinned at 32 with ~1 load in flight per wave).
// HW semantics (m104/m173): LDS dest = wave-uniform base + lane*16;
// global src addr is per-lane.
__device__ __forceinline__ void gload_lds16(const float* g, float4* lds) {
    __builtin_amdgcn_global_load_lds(
        (const __attribute__((address_space(1))) void*)g,
        (__attribute__((address_space(3))) void*)lds,
        16, 0, 0);
}

// One float4 group (4 consecutive pixels) per thread.
// The 8 mask streams (128 MB of the 224 MB footprint) are staged via
// global_load_lds: 8 async 1KB/wave loads guaranteed in flight -> ~8KB/wave,
// ~160KB/CU at 20 waves/CU, >> the ~10KB/CU Little's-law saturation point.
// x/y (6 loads) stay as plain register loads. __syncthreads() emits the
// vmcnt(0)+lgkmcnt(0) drain before s_barrier, so all staged data is visible.
__global__ __launch_bounds__(BLOCK_, 4) void pass1_kernel(
    const float* __restrict__ x, const float* __restrict__ y,
    const float* __restrict__ mk, double* __restrict__ acc)
{
    // 8 mask channels x 256 threads x 16B = 32 KB -> 5 blocks/CU, 20 waves/CU
    __shared__ float4 smM[8][BLOCK_];

    const int tid  = threadIdx.x;
    const int wave = tid >> 6;           // wave-uniform
    const int g    = blockIdx.x * BLOCK_ + tid;
    const int p0   = g << 2;
    const int b    = p0 >> 20;           // HW_ = 2^20
    const int hw   = p0 & (HW_ - 1);

    const size_t xb = (size_t)(b * 3) * HW_ + hw;
    const size_t mb = (size_t)(b * 8) * HW_ + hw;

    // ---- issue 8 async mask loads (in flight, no VGPR results) ----
#pragma unroll
    for (int c = 0; c < 8; ++c) {
        // dest base: wave-uniform; HW adds lane*16 -> smM[c][wave*64 + lane]
        gload_lds16(mk + mb + (size_t)c * HW_, &smM[c][wave << 6]);
    }

    // ---- x/y as plain register loads (overlap with the async masks) ----
    const float4 x0 = *(const float4*)(x + xb);
    const float4 x1 = *(const float4*)(x + xb + HW_);
    const float4 x2 = *(const float4*)(x + xb + 2 * (size_t)HW_);
    const float4 y0 = *(const float4*)(y + xb);
    const float4 y1 = *(const float4*)(y + xb + HW_);
    const float4 y2 = *(const float4*)(y + xb + 2 * (size_t)HW_);

    const float inv3 = 1.0f / 3.0f;
    float xav[4], yav[4];
    xav[0] = (x0.x + x1.x + x2.x) * inv3;
    xav[1] = (x0.y + x1.y + x2.y) * inv3;
    xav[2] = (x0.z + x1.z + x2.z) * inv3;
    xav[3] = (x0.w + x1.w + x2.w) * inv3;
    yav[0] = (y0.x + y1.x + y2.x) * inv3;
    yav[1] = (y0.y + y1.y + y2.y) * inv3;
    yav[2] = (y0.z + y1.z + y2.z) * inv3;
    yav[3] = (y0.w + y1.w + y2.w) * inv3;

    // Drain staged masks (emits s_waitcnt vmcnt(0) lgkmcnt(0) + s_barrier).
    __syncthreads();

    // ---- read back this thread's mask values from LDS ----
    const float4 m0 = smM[0][tid];
    const float4 m1 = smM[1][tid];
    const float4 m2 = smM[2][tid];
    const float4 m3 = smM[3][tid];
    const float4 m4 = smM[4][tid];
    const float4 m5 = smM[5][tid];
    const float4 m6 = smM[6][tid];
    const float4 m7 = smM[7][tid];

    float sx[8], sy[8], sc[8];
#pragma unroll
    for (int l = 0; l < 8; ++l) { sx[l] = 0.f; sy[l] = 0.f; sc[l] = 0.f; }
    float spw = 0.f, sxx = 0.f;

    // strict >: first occurrence wins (jnp.argmax tie-break)
#define PIX(F, J)                                                           \
    {                                                                       \
        float best = m0.F; int bi = 0;                                      \
        if (m1.F > best) { best = m1.F; bi = 1; }                           \
        if (m2.F > best) { best = m2.F; bi = 2; }                           \
        if (m3.F > best) { best = m3.F; bi = 3; }                           \
        if (m4.F > best) { best = m4.F; bi = 4; }                           \
        if (m5.F > best) { best = m5.F; bi = 5; }                           \
        if (m6.F > best) { best = m6.F; bi = 6; }                           \
        if (m7.F > best) { best = m7.F; bi = 7; }                           \
        _Pragma("unroll")                                                   \
        for (int l = 0; l < 8; ++l) {                                       \
            const bool p = (bi == l);                                       \
            sx[l] += p ? xav[J] : 0.0f;                                     \
            sy[l] += p ? yav[J] : 0.0f;                                     \
            sc[l] += p ? 1.0f : 0.0f;                                       \
        }                                                                   \
        spw += fast_pow_pos(xav[J], yav[J]);  /* xav>0: mean of uniforms */ \
        sxx += xav[J] * xav[J];                                             \
    }

    PIX(x, 0) PIX(y, 1) PIX(z, 2) PIX(w, 3)
#undef PIX

    // ---- wave64 shuffle reduction of the 26 accumulators ----
#pragma unroll
    for (int off = 32; off > 0; off >>= 1) {
#pragma unroll
        for (int l = 0; l < 8; ++l) {
            sx[l] += __shfl_down(sx[l], off);
            sy[l] += __shfl_down(sy[l], off);
            sc[l] += __shfl_down(sc[l], off);
        }
        spw += __shfl_down(spw, off);
        sxx += __shfl_down(sxx, off);
    }
    __shared__ float red[4][26];
    const int lane = tid & 63;
    if (lane == 0) {
#pragma unroll
        for (int l = 0; l < 8; ++l) {
            red[wave][l]      = sx[l];
            red[wave][8 + l]  = sy[l];
            red[wave][16 + l] = sc[l];
        }
        red[wave][24] = spw;
        red[wave][25] = sxx;
    }
    __syncthreads();
    if (tid < 26) {
        float t = red[0][tid] + red[1][tid] + red[2][tid] + red[3][tid];
        atomicAdd(&acc[(blockIdx.x & (NSETS - 1)) * ACC_STRIDE + tid],
                  (double)t);
    }
}

// ---- finalize: all three losses in f64, write 3 floats ----
__global__ void finalize_kernel(const double* __restrict__ acc,
                                float* __restrict__ out)
{
    __shared__ double sh[26];
    int t = threadIdx.x;
    if (t < 26) {
        double s = 0.0;
        for (int k = 0; k < NSETS; ++k) s += acc[k * ACC_STRIDE + t];
        sh[t] = s;
    }
    __syncthreads();
    if (t == 0) {
        const double invN = 1.0 / (double)NPIX;
        double l1 = sh[24];       // sum of pow over on-mask pixels
        double l3 = sh[25];       // sum of xa^2
        double l2 = 0.0;
        for (int l = 0; l < 8; ++l) {
            double SX  = sh[l];
            double XA  = SX * invN;
            double YA  = sh[8 + l] * invN;
            double cnt = sh[16 + l];
            double pw  = pow(XA, YA);
            l2 += pw;
            l1 += ((double)NPIX - cnt) * pw;          // off-mask pow terms
            l3 += cnt * XA * XA - 2.0 * XA * SX;      // per-label variance cross terms
        }
        out[0] = (float)(l1 * invN);
        out[1] = (float)l2;
        out[2] = (float)(l3 * invN);
    }
}

extern "C" void kernel_launch(void* const* d_in, const int* in_sizes, int n_in,
                              void* d_out, int out_size, void* d_ws, size_t ws_size,
                              hipStream_t stream)
{
    const float* x  = (const float*)d_in[0];
    const float* y  = (const float*)d_in[1];
    const float* mk = (const float*)d_in[2];
    float* out = (float*)d_out;

    double* acc = (double*)d_ws;                    // 64*32*8 = 16 KB
    (void)hipMemsetAsync(acc, 0, NSETS * ACC_STRIDE * 8, stream);

    pass1_kernel<<<GRID1, BLOCK_, 0, stream>>>(x, y, mk, acc);
    finalize_kernel<<<1, 64, 0, stream>>>(acc, out);
}

// Round 7
// 265.554 us; speedup vs baseline: 1.0238x; 1.0149x over previous
//
#include <hip/hip_runtime.h>
#include <math.h>

#define HW_     (1024 * 1024)
#define NPIX    (4 * HW_)               // 4,194,304 pixels
#define NG      (NPIX / 4)              // 1,048,576 float4 groups
#define NSETS   64
#define ACC_STRIDE 32                   // doubles/set: 0..7 sx, 8..15 sy, 16..23 cnt, 24 spw, 25 sxx
#define BLOCK_  256
#define TILE_G  1024                    // groups per block tile (16 KB/plane/block)
#define RUN     4                       // consecutive 1KB wave-loads per plane
#define GRID1   (NG / TILE_G)           // 1024 blocks (= 4 per CU)

// fast pow for x>0: v_log_f32 (log2) + v_mul + v_exp_f32 (exp2)
__device__ __forceinline__ float fast_pow_pos(float x, float p) {
    return __builtin_amdgcn_exp2f(p * __builtin_amdgcn_logf(x));
}

// Round 7: DE-INTERLEAVED, PLANE-MAJOR TRAVERSAL.
// R6 falsified the per-wave-MLP theory (8 guaranteed in-flight loads, zero BW
// gain) -> the memory system is service-rate-limited for the old pattern:
// every thread burst touched 14 streams exactly 4MB apart (power-of-two ->
// DRAM channel/bank aliasing, 14 interleaved rows per bank queue, row-buffer
// thrash). This version keeps bytes identical but reorders: plane-OUTER,
// run-INNER. Each wave reads 4 consecutive 1KB chunks (4KB contiguous) from
// ONE plane before switching planes; a block covers 16KB contiguous per
// plane. Running x/y sums and mask argmax carry across planes in registers.
__global__ __launch_bounds__(BLOCK_, 4) void pass1_kernel(
    const float* __restrict__ x, const float* __restrict__ y,
    const float* __restrict__ mk, double* __restrict__ acc)
{
    const int tid  = threadIdx.x;
    const int wave = tid >> 6, lane = tid & 63;
    const int t    = blockIdx.x;            // 0..1023
    const int b    = t >> 8;                // 256 tiles per batch
    // float offset of this thread's r=0 chunk inside a plane:
    const size_t hw0 = (size_t)(t & 255) * 4096 + (size_t)wave * 1024
                     + (size_t)lane * 4;

    const float* xp = x  + (size_t)(b * 3) * HW_ + hw0;
    const float* yp = y  + (size_t)(b * 3) * HW_ + hw0;
    const float* mp = mk + (size_t)(b * 8) * HW_ + hw0;

    // ---- x planes: plane-major, 4KB contiguous per wave per plane ----
    float4 xs[RUN], ys[RUN];
#pragma unroll
    for (int r = 0; r < RUN; ++r) xs[r] = *(const float4*)(xp + r * 256);
#pragma unroll
    for (int c = 1; c < 3; ++c) {
        __builtin_amdgcn_sched_barrier(0);  // keep plane sections in order
#pragma unroll
        for (int r = 0; r < RUN; ++r) {
            const float4 v = *(const float4*)(xp + (size_t)c * HW_ + r * 256);
            xs[r].x += v.x; xs[r].y += v.y; xs[r].z += v.z; xs[r].w += v.w;
        }
    }
    __builtin_amdgcn_sched_barrier(0);
    // ---- y planes ----
#pragma unroll
    for (int r = 0; r < RUN; ++r) ys[r] = *(const float4*)(yp + r * 256);
#pragma unroll
    for (int c = 1; c < 3; ++c) {
        __builtin_amdgcn_sched_barrier(0);
#pragma unroll
        for (int r = 0; r < RUN; ++r) {
            const float4 v = *(const float4*)(yp + (size_t)c * HW_ + r * 256);
            ys[r].x += v.x; ys[r].y += v.y; ys[r].z += v.z; ys[r].w += v.w;
        }
    }
    const float inv3 = 1.0f / 3.0f;
#pragma unroll
    for (int r = 0; r < RUN; ++r) {
        xs[r].x *= inv3; xs[r].y *= inv3; xs[r].z *= inv3; xs[r].w *= inv3;
        ys[r].x *= inv3; ys[r].y *= inv3; ys[r].z *= inv3; ys[r].w *= inv3;
    }

    // ---- mask planes: plane-major running argmax ----
    // strict >: first occurrence wins (jnp.argmax tie-break, c ascending)
    float4 best[RUN]; int4 bi[RUN];
    __builtin_amdgcn_sched_barrier(0);
#pragma unroll
    for (int r = 0; r < RUN; ++r) {
        best[r] = *(const float4*)(mp + r * 256);
        bi[r].x = 0; bi[r].y = 0; bi[r].z = 0; bi[r].w = 0;
    }
#pragma unroll
    for (int c = 1; c < 8; ++c) {
        __builtin_amdgcn_sched_barrier(0);
#pragma unroll
        for (int r = 0; r < RUN; ++r) {
            const float4 v = *(const float4*)(mp + (size_t)c * HW_ + r * 256);
            if (v.x > best[r].x) { best[r].x = v.x; bi[r].x = c; }
            if (v.y > best[r].y) { best[r].y = v.y; bi[r].y = c; }
            if (v.z > best[r].z) { best[r].z = v.z; bi[r].z = c; }
            if (v.w > best[r].w) { best[r].w = v.w; bi[r].w = c; }
        }
    }

    // ---- accumulate 16 pixels into the 26 per-thread accumulators ----
    float sx[8], sy[8], sc[8];
#pragma unroll
    for (int l = 0; l < 8; ++l) { sx[l] = 0.f; sy[l] = 0.f; sc[l] = 0.f; }
    float spw = 0.f, sxx = 0.f;

#define PIX(R, F)                                                           \
    {                                                                       \
        const float xav = xs[R].F;                                          \
        const float yav = ys[R].F;                                          \
        const int   lab = bi[R].F;                                          \
        _Pragma("unroll")                                                   \
        for (int l = 0; l < 8; ++l) {                                       \
            const bool p = (lab == l);                                      \
            sx[l] += p ? xav : 0.0f;                                        \
            sy[l] += p ? yav : 0.0f;                                        \
            sc[l] += p ? 1.0f : 0.0f;                                       \
        }                                                                   \
        spw += fast_pow_pos(xav, yav);  /* xav>0: mean of uniforms */       \
        sxx += xav * xav;                                                   \
    }

#pragma unroll
    for (int r = 0; r < RUN; ++r) { PIX(r, x) PIX(r, y) PIX(r, z) PIX(r, w) }
#undef PIX

    // ---- wave64 shuffle reduction of the 26 accumulators ----
#pragma unroll
    for (int off = 32; off > 0; off >>= 1) {
#pragma unroll
        for (int l = 0; l < 8; ++l) {
            sx[l] += __shfl_down(sx[l], off);
            sy[l] += __shfl_down(sy[l], off);
            sc[l] += __shfl_down(sc[l], off);
        }
        spw += __shfl_down(spw, off);
        sxx += __shfl_down(sxx, off);
    }
    __shared__ float red[4][26];
    if (lane == 0) {
#pragma unroll
        for (int l = 0; l < 8; ++l) {
            red[wave][l]      = sx[l];
            red[wave][8 + l]  = sy[l];
            red[wave][16 + l] = sc[l];
        }
        red[wave][24] = spw;
        red[wave][25] = sxx;
    }
    __syncthreads();
    if (tid < 26) {
        float s = red[0][tid] + red[1][tid] + red[2][tid] + red[3][tid];
        atomicAdd(&acc[(blockIdx.x & (NSETS - 1)) * ACC_STRIDE + tid],
                  (double)s);
    }
}

// ---- finalize: all three losses in f64, write 3 floats ----
__global__ void finalize_kernel(const double* __restrict__ acc,
                                float* __restrict__ out)
{
    __shared__ double sh[26];
    int t = threadIdx.x;
    if (t < 26) {
        double s = 0.0;
        for (int k = 0; k < NSETS; ++k) s += acc[k * ACC_STRIDE + t];
        sh[t] = s;
    }
    __syncthreads();
    if (t == 0) {
        const double invN = 1.0 / (double)NPIX;
        double l1 = sh[24];       // sum of pow over on-mask pixels
        double l3 = sh[25];       // sum of xa^2
        double l2 = 0.0;
        for (int l = 0; l < 8; ++l) {
            double SX  = sh[l];
            double XA  = SX * invN;
            double YA  = sh[8 + l] * invN;
            double cnt = sh[16 + l];
            double pw  = pow(XA, YA);
            l2 += pw;
            l1 += ((double)NPIX - cnt) * pw;          // off-mask pow terms
            l3 += cnt * XA * XA - 2.0 * XA * SX;      // per-label variance cross terms
        }
        out[0] = (float)(l1 * invN);
        out[1] = (float)l2;
        out[2] = (float)(l3 * invN);
    }
}

extern "C" void kernel_launch(void* const* d_in, const int* in_sizes, int n_in,
                              void* d_out, int out_size, void* d_ws, size_t ws_size,
                              hipStream_t stream)
{
    const float* x  = (const float*)d_in[0];
    const float* y  = (const float*)d_in[1];
    const float* mk = (const float*)d_in[2];
    float* out = (float*)d_out;

    double* acc = (double*)d_ws;                    // 64*32*8 = 16 KB
    (void)hipMemsetAsync(acc, 0, NSETS * ACC_STRIDE * 8, stream);

    pass1_kernel<<<GRID1, BLOCK_, 0, stream>>>(x, y, mk, acc);
    finalize_kernel<<<1, 64, 0, stream>>>(acc, out);
}

// Round 9
// 256.550 us; speedup vs baseline: 1.0598x; 1.0351x over previous
//
#include <hip/hip_runtime.h>
#include <math.h>

#define HW_     (1024 * 1024)
#define NPIX    (4 * HW_)               // 4,194,304 pixels
#define NG      (NPIX / 4)              // 1,048,576 float4 groups
#define NSETS   64
#define ACC_STRIDE 32                   // doubles/set: 0..7 sx, 8..15 sy, 16..23 cnt, 24 spw, 25 sxx
#define BLOCK_  256
#define TILE_G  1024                    // groups per block tile (16 KB/plane/block)
#define RUN     4                       // consecutive 1KB wave-loads per plane
#define GRID1   (NG / TILE_G)           // 1024 blocks (= 4 per CU)

// Native clang vector type: __builtin_nontemporal_load requires a pointer to
// scalar/pointer/VECTOR type -- HIP_vector_type (float4) is a struct and is
// rejected (round 8 compile error). f32x4 is layout-identical to float4.
typedef float f32x4 __attribute__((ext_vector_type(4)));

// fast pow for x>0: v_log_f32 (log2) + v_mul + v_exp_f32 (exp2)
__device__ __forceinline__ float fast_pow_pos(float x, float p) {
    return __builtin_amdgcn_exp2f(p * __builtin_amdgcn_logf(x));
}

// Round 9 (= round 8 retry): MASK STREAM NON-TEMPORAL.
// Ledger R0-R7: delivered BW pinned at 2.4-2.5 TB/s, insensitive to occupancy
// (64%<->32%), per-wave MLP (1->8 guaranteed in-flight, R6), request order
// (interleaved vs plane-major linear, R7), and destination (VGPR vs LDS).
// Supply-side limits are ruled out; FETCH_SIZE=117MB of 224MB means ~107MB/
// iter are L3 hits (224MB footprint vs 256MB MALL -> ~50% retention churn).
// Last untouched knob: allocation policy. Masks (128MB, 57% of footprint) are
// the churn: nt-load them so x+y (96MB) become fully L3-resident and MALL
// allocation churn stops. Identical structure to R7 otherwise (clean A/B).
__global__ __launch_bounds__(BLOCK_, 4) void pass1_kernel(
    const float* __restrict__ x, const float* __restrict__ y,
    const float* __restrict__ mk, double* __restrict__ acc)
{
    const int tid  = threadIdx.x;
    const int wave = tid >> 6, lane = tid & 63;
    const int t    = blockIdx.x;            // 0..1023
    const int b    = t >> 8;                // 256 tiles per batch
    // float offset of this thread's r=0 chunk inside a plane:
    const size_t hw0 = (size_t)(t & 255) * 4096 + (size_t)wave * 1024
                     + (size_t)lane * 4;

    const float* xp = x  + (size_t)(b * 3) * HW_ + hw0;
    const float* yp = y  + (size_t)(b * 3) * HW_ + hw0;
    const float* mp = mk + (size_t)(b * 8) * HW_ + hw0;

    // ---- x planes: plane-major, 4KB contiguous per wave per plane ----
    f32x4 xs[RUN], ys[RUN];
#pragma unroll
    for (int r = 0; r < RUN; ++r) xs[r] = *(const f32x4*)(xp + r * 256);
#pragma unroll
    for (int c = 1; c < 3; ++c) {
        __builtin_amdgcn_sched_barrier(0);  // keep plane sections in order
#pragma unroll
        for (int r = 0; r < RUN; ++r)
            xs[r] += *(const f32x4*)(xp + (size_t)c * HW_ + r * 256);
    }
    __builtin_amdgcn_sched_barrier(0);
    // ---- y planes ----
#pragma unroll
    for (int r = 0; r < RUN; ++r) ys[r] = *(const f32x4*)(yp + r * 256);
#pragma unroll
    for (int c = 1; c < 3; ++c) {
        __builtin_amdgcn_sched_barrier(0);
#pragma unroll
        for (int r = 0; r < RUN; ++r)
            ys[r] += *(const f32x4*)(yp + (size_t)c * HW_ + r * 256);
    }
    const float inv3 = 1.0f / 3.0f;
#pragma unroll
    for (int r = 0; r < RUN; ++r) { xs[r] *= inv3; ys[r] *= inv3; }

    // ---- mask planes: NON-TEMPORAL plane-major running argmax ----
    // strict >: first occurrence wins (jnp.argmax tie-break, c ascending)
    f32x4 best[RUN]; int4 bi[RUN];
    __builtin_amdgcn_sched_barrier(0);
#pragma unroll
    for (int r = 0; r < RUN; ++r) {
        best[r] = __builtin_nontemporal_load((const f32x4*)(mp + r * 256));
        bi[r].x = 0; bi[r].y = 0; bi[r].z = 0; bi[r].w = 0;
    }
#pragma unroll
    for (int c = 1; c < 8; ++c) {
        __builtin_amdgcn_sched_barrier(0);
#pragma unroll
        for (int r = 0; r < RUN; ++r) {
            const f32x4 v = __builtin_nontemporal_load(
                (const f32x4*)(mp + (size_t)c * HW_ + r * 256));
            if (v.x > best[r].x) { best[r].x = v.x; bi[r].x = c; }
            if (v.y > best[r].y) { best[r].y = v.y; bi[r].y = c; }
            if (v.z > best[r].z) { best[r].z = v.z; bi[r].z = c; }
            if (v.w > best[r].w) { best[r].w = v.w; bi[r].w = c; }
        }
    }

    // ---- accumulate 16 pixels into the 26 per-thread accumulators ----
    float sx[8], sy[8], sc[8];
#pragma unroll
    for (int l = 0; l < 8; ++l) { sx[l] = 0.f; sy[l] = 0.f; sc[l] = 0.f; }
    float spw = 0.f, sxx = 0.f;

#define PIX(R, F)                                                           \
    {                                                                       \
        const float xav = xs[R].F;                                          \
        const float yav = ys[R].F;                                          \
        const int   lab = bi[R].F;                                          \
        _Pragma("unroll")                                                   \
        for (int l = 0; l < 8; ++l) {                                       \
            const bool p = (lab == l);                                      \
            sx[l] += p ? xav : 0.0f;                                        \
            sy[l] += p ? yav : 0.0f;                                        \
            sc[l] += p ? 1.0f : 0.0f;                                       \
        }                                                                   \
        spw += fast_pow_pos(xav, yav);  /* xav>0: mean of uniforms */       \
        sxx += xav * xav;                                                   \
    }

#pragma unroll
    for (int r = 0; r < RUN; ++r) { PIX(r, x) PIX(r, y) PIX(r, z) PIX(r, w) }
#undef PIX

    // ---- wave64 shuffle reduction of the 26 accumulators ----
#pragma unroll
    for (int off = 32; off > 0; off >>= 1) {
#pragma unroll
        for (int l = 0; l < 8; ++l) {
            sx[l] += __shfl_down(sx[l], off);
            sy[l] += __shfl_down(sy[l], off);
            sc[l] += __shfl_down(sc[l], off);
        }
        spw += __shfl_down(spw, off);
        sxx += __shfl_down(sxx, off);
    }
    __shared__ float red[4][26];
    if (lane == 0) {
#pragma unroll
        for (int l = 0; l < 8; ++l) {
            red[wave][l]      = sx[l];
            red[wave][8 + l]  = sy[l];
            red[wave][16 + l] = sc[l];
        }
        red[wave][24] = spw;
        red[wave][25] = sxx;
    }
    __syncthreads();
    if (tid < 26) {
        float s = red[0][tid] + red[1][tid] + red[2][tid] + red[3][tid];
        atomicAdd(&acc[(blockIdx.x & (NSETS - 1)) * ACC_STRIDE + tid],
                  (double)s);
    }
}

// ---- finalize: all three losses in f64, write 3 floats ----
__global__ void finalize_kernel(const double* __restrict__ acc,
                                float* __restrict__ out)
{
    __shared__ double sh[26];
    int t = threadIdx.x;
    if (t < 26) {
        double s = 0.0;
        for (int k = 0; k < NSETS; ++k) s += acc[k * ACC_STRIDE + t];
        sh[t] = s;
    }
    __syncthreads();
    if (t == 0) {
        const double invN = 1.0 / (double)NPIX;
        double l1 = sh[24];       // sum of pow over on-mask pixels
        double l3 = sh[25];       // sum of xa^2
        double l2 = 0.0;
        for (int l = 0; l < 8; ++l) {
            double SX  = sh[l];
            double XA  = SX * invN;
            double YA  = sh[8 + l] * invN;
            double cnt = sh[16 + l];
            double pw  = pow(XA, YA);
            l2 += pw;
            l1 += ((double)NPIX - cnt) * pw;          // off-mask pow terms
            l3 += cnt * XA * XA - 2.0 * XA * SX;      // per-label variance cross terms
        }
        out[0] = (float)(l1 * invN);
        out[1] = (float)l2;
        out[2] = (float)(l3 * invN);
    }
}

extern "C" void kernel_launch(void* const* d_in, const int* in_sizes, int n_in,
                              void* d_out, int out_size, void* d_ws, size_t ws_size,
                              hipStream_t stream)
{
    const float* x  = (const float*)d_in[0];
    const float* y  = (const float*)d_in[1];
    const float* mk = (const float*)d_in[2];
    float* out = (float*)d_out;

    double* acc = (double*)d_ws;                    // 64*32*8 = 16 KB
    (void)hipMemsetAsync(acc, 0, NSETS * ACC_STRIDE * 8, stream);

    pass1_kernel<<<GRID1, BLOCK_, 0, stream>>>(x, y, mk, acc);
    finalize_kernel<<<1, 64, 0, stream>>>(acc, out);
}

// Round 10
// 241.106 us; speedup vs baseline: 1.1276x; 1.0641x over previous
//
#include <hip/hip_runtime.h>
#include <math.h>

#define HW_     (1024 * 1024)
#define NPIX    (4 * HW_)               // 4,194,304 pixels
#define NG      (NPIX / 4)              // 1,048,576 float4 groups
#define NSETS   64
#define ACC_STRIDE 32                   // doubles/set: 0..7 sx, 8..15 sy, 16..23 cnt, 24 spw, 25 sxx
#define BLOCK_  256
#define TILE_G  1024                    // groups per block tile (16 KB/plane/block)
#define RUN     4                       // consecutive 1KB wave-loads per plane
#define GRID1   (NG / TILE_G)           // 1024 blocks (= 4 per CU)

// Native clang vector type: __builtin_nontemporal_load requires a pointer to
// scalar/pointer/VECTOR type -- HIP_vector_type (float4) is rejected.
typedef float f32x4 __attribute__((ext_vector_type(4)));

// fast pow for x>0: v_log_f32 (log2) + v_mul + v_exp_f32 (exp2)
__device__ __forceinline__ float fast_pow_pos(float x, float p) {
    return __builtin_amdgcn_exp2f(p * __builtin_amdgcn_logf(x));
}

// Round 10: ALL STREAMS NON-TEMPORAL.
// R9 (masks-only nt) gave the first real movement of the session: pass1
// ~90->~81us, e2e 265.5->256.6. Allocation policy is the operative knob --
// confirming the MALL-churn theory. Residual question: is the remaining drag
// (a) the L3 hit/miss interleave pacing the waves, or (b) an HBM read cap?
// This round: nt on x,y too -> zero L3 allocation, pure streaming reads,
// the same regime as the 6.3 TB/s copy ubench. Single-variable A/B vs R9.
__global__ __launch_bounds__(BLOCK_, 4) void pass1_kernel(
    const float* __restrict__ x, const float* __restrict__ y,
    const float* __restrict__ mk, double* __restrict__ acc)
{
    const int tid  = threadIdx.x;
    const int wave = tid >> 6, lane = tid & 63;
    const int t    = blockIdx.x;            // 0..1023
    const int b    = t >> 8;                // 256 tiles per batch
    // float offset of this thread's r=0 chunk inside a plane:
    const size_t hw0 = (size_t)(t & 255) * 4096 + (size_t)wave * 1024
                     + (size_t)lane * 4;

    const float* xp = x  + (size_t)(b * 3) * HW_ + hw0;
    const float* yp = y  + (size_t)(b * 3) * HW_ + hw0;
    const float* mp = mk + (size_t)(b * 8) * HW_ + hw0;

    // ---- x planes: plane-major, 4KB contiguous per wave per plane ----
    f32x4 xs[RUN], ys[RUN];
#pragma unroll
    for (int r = 0; r < RUN; ++r)
        xs[r] = __builtin_nontemporal_load((const f32x4*)(xp + r * 256));
#pragma unroll
    for (int c = 1; c < 3; ++c) {
        __builtin_amdgcn_sched_barrier(0);  // keep plane sections in order
#pragma unroll
        for (int r = 0; r < RUN; ++r)
            xs[r] += __builtin_nontemporal_load(
                (const f32x4*)(xp + (size_t)c * HW_ + r * 256));
    }
    __builtin_amdgcn_sched_barrier(0);
    // ---- y planes ----
#pragma unroll
    for (int r = 0; r < RUN; ++r)
        ys[r] = __builtin_nontemporal_load((const f32x4*)(yp + r * 256));
#pragma unroll
    for (int c = 1; c < 3; ++c) {
        __builtin_amdgcn_sched_barrier(0);
#pragma unroll
        for (int r = 0; r < RUN; ++r)
            ys[r] += __builtin_nontemporal_load(
                (const f32x4*)(yp + (size_t)c * HW_ + r * 256));
    }
    const float inv3 = 1.0f / 3.0f;
#pragma unroll
    for (int r = 0; r < RUN; ++r) { xs[r] *= inv3; ys[r] *= inv3; }

    // ---- mask planes: NON-TEMPORAL plane-major running argmax ----
    // strict >: first occurrence wins (jnp.argmax tie-break, c ascending)
    f32x4 best[RUN]; int4 bi[RUN];
    __builtin_amdgcn_sched_barrier(0);
#pragma unroll
    for (int r = 0; r < RUN; ++r) {
        best[r] = __builtin_nontemporal_load((const f32x4*)(mp + r * 256));
        bi[r].x = 0; bi[r].y = 0; bi[r].z = 0; bi[r].w = 0;
    }
#pragma unroll
    for (int c = 1; c < 8; ++c) {
        __builtin_amdgcn_sched_barrier(0);
#pragma unroll
        for (int r = 0; r < RUN; ++r) {
            const f32x4 v = __builtin_nontemporal_load(
                (const f32x4*)(mp + (size_t)c * HW_ + r * 256));
            if (v.x > best[r].x) { best[r].x = v.x; bi[r].x = c; }
            if (v.y > best[r].y) { best[r].y = v.y; bi[r].y = c; }
            if (v.z > best[r].z) { best[r].z = v.z; bi[r].z = c; }
            if (v.w > best[r].w) { best[r].w = v.w; bi[r].w = c; }
        }
    }

    // ---- accumulate 16 pixels into the 26 per-thread accumulators ----
    float sx[8], sy[8], sc[8];
#pragma unroll
    for (int l = 0; l < 8; ++l) { sx[l] = 0.f; sy[l] = 0.f; sc[l] = 0.f; }
    float spw = 0.f, sxx = 0.f;

#define PIX(R, F)                                                           \
    {                                                                       \
        const float xav = xs[R].F;                                          \
        const float yav = ys[R].F;                                          \
        const int   lab = bi[R].F;                                          \
        _Pragma("unroll")                                                   \
        for (int l = 0; l < 8; ++l) {                                       \
            const bool p = (lab == l);                                      \
            sx[l] += p ? xav : 0.0f;                                        \
            sy[l] += p ? yav : 0.0f;                                        \
            sc[l] += p ? 1.0f : 0.0f;                                       \
        }                                                                   \
        spw += fast_pow_pos(xav, yav);  /* xav>0: mean of uniforms */       \
        sxx += xav * xav;                                                   \
    }

#pragma unroll
    for (int r = 0; r < RUN; ++r) { PIX(r, x) PIX(r, y) PIX(r, z) PIX(r, w) }
#undef PIX

    // ---- wave64 shuffle reduction of the 26 accumulators ----
#pragma unroll
    for (int off = 32; off > 0; off >>= 1) {
#pragma unroll
        for (int l = 0; l < 8; ++l) {
            sx[l] += __shfl_down(sx[l], off);
            sy[l] += __shfl_down(sy[l], off);
            sc[l] += __shfl_down(sc[l], off);
        }
        spw += __shfl_down(spw, off);
        sxx += __shfl_down(sxx, off);
    }
    __shared__ float red[4][26];
    if (lane == 0) {
#pragma unroll
        for (int l = 0; l < 8; ++l) {
            red[wave][l]      = sx[l];
            red[wave][8 + l]  = sy[l];
            red[wave][16 + l] = sc[l];
        }
        red[wave][24] = spw;
        red[wave][25] = sxx;
    }
    __syncthreads();
    if (tid < 26) {
        float s = red[0][tid] + red[1][tid] + red[2][tid] + red[3][tid];
        atomicAdd(&acc[(blockIdx.x & (NSETS - 1)) * ACC_STRIDE + tid],
                  (double)s);
    }
}

// ---- finalize: all three losses in f64, write 3 floats ----
__global__ void finalize_kernel(const double* __restrict__ acc,
                                float* __restrict__ out)
{
    __shared__ double sh[26];
    int t = threadIdx.x;
    if (t < 26) {
        double s = 0.0;
        for (int k = 0; k < NSETS; ++k) s += acc[k * ACC_STRIDE + t];
        sh[t] = s;
    }
    __syncthreads();
    if (t == 0) {
        const double invN = 1.0 / (double)NPIX;
        double l1 = sh[24];       // sum of pow over on-mask pixels
        double l3 = sh[25];       // sum of xa^2
        double l2 = 0.0;
        for (int l = 0; l < 8; ++l) {
            double SX  = sh[l];
            double XA  = SX * invN;
            double YA  = sh[8 + l] * invN;
            double cnt = sh[16 + l];
            double pw  = pow(XA, YA);
            l2 += pw;
            l1 += ((double)NPIX - cnt) * pw;          // off-mask pow terms
            l3 += cnt * XA * XA - 2.0 * XA * SX;      // per-label variance cross terms
        }
        out[0] = (float)(l1 * invN);
        out[1] = (float)l2;
        out[2] = (float)(l3 * invN);
    }
}

extern "C" void kernel_launch(void* const* d_in, const int* in_sizes, int n_in,
                              void* d_out, int out_size, void* d_ws, size_t ws_size,
                              hipStream_t stream)
{
    const float* x  = (const float*)d_in[0];
    const float* y  = (const float*)d_in[1];
    const float* mk = (const float*)d_in[2];
    float* out = (float*)d_out;

    double* acc = (double*)d_ws;                    // 64*32*8 = 16 KB
    (void)hipMemsetAsync(acc, 0, NSETS * ACC_STRIDE * 8, stream);

    pass1_kernel<<<GRID1, BLOCK_, 0, stream>>>(x, y, mk, acc);
    finalize_kernel<<<1, 64, 0, stream>>>(acc, out);
}